// Round 1
// baseline (417.487 us; speedup 1.0000x reference)
//
#include <hip/hip_runtime.h>

// y[n] = beta0 + sum_c X[n,c] * (beta[c] + Z[n,c]),  Z = X @ triu(Theta,1)
// Fused bf16-MFMA GEMM with triangular K-skip + epilogue row-dot.
// N=65536, P=1024, f32 in/out. Block = 128x128 tile, 4 waves (2x2), 16x16x32 bf16 MFMA.

typedef __bf16 bf16_t;
typedef bf16_t bf16x8 __attribute__((ext_vector_type(8)));
typedef float f32x4 __attribute__((ext_vector_type(4)));
typedef unsigned short u16;
typedef u16 u16x4 __attribute__((ext_vector_type(4)));
typedef u16 u16x8 __attribute__((ext_vector_type(8)));

#define N_ROWS 65536
#define P_DIM  1024
#define BM 128
#define BN 128
#define BK 32
#define LDT 40  // padded LDS row stride (bf16 elems): 80 B rows -> 16B-aligned, ~2-way bank aliasing (free)

static __device__ __forceinline__ u16 f2bf(float f) {
  unsigned u = __builtin_bit_cast(unsigned, f);
  u += 0x7FFFu + ((u >> 16) & 1u);   // round-to-nearest-even
  return (u16)(u >> 16);
}

__global__ void __launch_bounds__(256)
init_y(float* __restrict__ y, const float* __restrict__ beta0) {
  int i = blockIdx.x * blockDim.x + threadIdx.x;
  if (i < N_ROWS) y[i] = beta0[0];
}

__global__ void __launch_bounds__(256)
fused_quad_kernel(const float* __restrict__ X, const float* __restrict__ beta,
                  const float* __restrict__ Theta, float* __restrict__ y)
{
  __shared__ __align__(16) u16 Alds[BM * LDT];
  __shared__ __align__(16) u16 Blds[BN * LDT];

  const int bid = blockIdx.x;
  const int bn  = bid & 7;        // column block 0..7 (mixes K-lengths across CUs)
  const int bm  = bid >> 3;       // row block 0..511
  const int c0  = bn * BN;
  const int m0  = bm * BM;
  const int nkt = (bn + 1) * (BN / BK);   // triangular K-skip: K runs only to c0+BN

  const int tid  = threadIdx.x;
  const int lane = tid & 63;
  const int wid  = tid >> 6;
  const int wm   = wid >> 1;      // wave row 0..1 (64 rows each)
  const int wn   = wid & 1;       // wave col 0..1 (64 cols each)
  const int l15  = lane & 15;
  const int lg   = lane >> 4;

  f32x4 acc[4][4];
  #pragma unroll
  for (int i = 0; i < 4; ++i)
    #pragma unroll
    for (int j = 0; j < 4; ++j)
      acc[i][j] = (f32x4)0.0f;

  // A staging: 2 threads per row, 16 f32 each
  const int arow  = tid >> 1;           // 0..127
  const int ahalf = (tid & 1) * 16;     // 0 or 16
  // B staging: 4x4 micro-tile transpose; 8 k-blocks x 32 c-blocks
  const int kb4 = (tid >> 5) * 4;       // k_local base 0..28
  const int cb4 = (tid & 31) * 4;       // c_local base 0..124

  for (int kt = 0; kt < nkt; ++kt) {
    const int k0 = kt * BK;
    __syncthreads();   // protect LDS from previous iteration's readers

    // ---- stage A: X[m0..m0+128, k0..k0+32) -> bf16, [row][k] padded ----
    {
      const f32x4* p = (const f32x4*)(X + (size_t)(m0 + arow) * P_DIM + k0 + ahalf);
      f32x4 v0 = p[0], v1 = p[1], v2 = p[2], v3 = p[3];
      u16x8 w0, w1;
      #pragma unroll
      for (int i = 0; i < 4; ++i) {
        w0[i]     = f2bf(v0[i]);
        w0[i + 4] = f2bf(v1[i]);
        w1[i]     = f2bf(v2[i]);
        w1[i + 4] = f2bf(v3[i]);
      }
      *(u16x8*)&Alds[arow * LDT + ahalf]     = w0;
      *(u16x8*)&Alds[arow * LDT + ahalf + 8] = w1;
    }

    // ---- stage B: triu(Theta,1)[k0..k0+32, c0..c0+128) -> bf16, stored [col][k] ----
    {
      float e[4][4];
      #pragma unroll
      for (int i = 0; i < 4; ++i) {
        f32x4 r = *(const f32x4*)(Theta + (size_t)(k0 + kb4 + i) * P_DIM + c0 + cb4);
        #pragma unroll
        for (int j = 0; j < 4; ++j)
          e[i][j] = ((k0 + kb4 + i) < (c0 + cb4 + j)) ? r[j] : 0.0f;  // strict upper mask
      }
      #pragma unroll
      for (int j = 0; j < 4; ++j) {
        u16x4 wv;
        #pragma unroll
        for (int i = 0; i < 4; ++i) wv[i] = f2bf(e[i][j]);
        *(u16x4*)&Blds[(cb4 + j) * LDT + kb4] = wv;
      }
    }
    __syncthreads();

    // ---- MFMA: acc[mi][ni] += A(16x32) * B(32x16) ----
    bf16x8 af[4], bfr[4];
    #pragma unroll
    for (int mi = 0; mi < 4; ++mi) {
      u16x8 t = *(const u16x8*)&Alds[(wm * 64 + mi * 16 + l15) * LDT + lg * 8];
      af[mi] = __builtin_bit_cast(bf16x8, t);
    }
    #pragma unroll
    for (int ni = 0; ni < 4; ++ni) {
      u16x8 t = *(const u16x8*)&Blds[(wn * 64 + ni * 16 + l15) * LDT + lg * 8];
      bfr[ni] = __builtin_bit_cast(bf16x8, t);
    }
    #pragma unroll
    for (int mi = 0; mi < 4; ++mi)
      #pragma unroll
      for (int ni = 0; ni < 4; ++ni)
        acc[mi][ni] = __builtin_amdgcn_mfma_f32_16x16x32_bf16(af[mi], bfr[ni], acc[mi][ni], 0, 0, 0);
  }

  // ---- epilogue: y_partial[row] = sum_c (Z[row,c] + beta[c]) * X[row,c] ----
  // C/D layout (m89-verified): col = lane&15, row = (lane>>4)*4 + reg
  float ysum[4][4];   // [mi][reg]
  #pragma unroll
  for (int mi = 0; mi < 4; ++mi)
    #pragma unroll
    for (int r = 0; r < 4; ++r)
      ysum[mi][r] = 0.0f;

  #pragma unroll
  for (int ni = 0; ni < 4; ++ni) {
    const int col = c0 + wn * 64 + ni * 16 + l15;
    const float bta = beta[col];
    #pragma unroll
    for (int mi = 0; mi < 4; ++mi) {
      const int rowb = m0 + wm * 64 + mi * 16 + lg * 4;
      #pragma unroll
      for (int r = 0; r < 4; ++r) {
        float xv = X[(size_t)(rowb + r) * P_DIM + col];   // L2-hot: last K-tiles just read it
        ysum[mi][r] += (acc[mi][ni][r] + bta) * xv;
      }
    }
  }

  // reduce across the 16 lanes of each lane-group (cols), then atomically add per row
  #pragma unroll
  for (int m = 1; m < 16; m <<= 1)
    #pragma unroll
    for (int mi = 0; mi < 4; ++mi)
      #pragma unroll
      for (int r = 0; r < 4; ++r)
        ysum[mi][r] += __shfl_xor(ysum[mi][r], m);

  if (l15 == 0) {
    #pragma unroll
    for (int mi = 0; mi < 4; ++mi)
      #pragma unroll
      for (int r = 0; r < 4; ++r)
        atomicAdd(&y[m0 + wm * 64 + mi * 16 + lg * 4 + r], ysum[mi][r]);
  }
}

extern "C" void kernel_launch(void* const* d_in, const int* in_sizes, int n_in,
                              void* d_out, int out_size, void* d_ws, size_t ws_size,
                              hipStream_t stream) {
  const float* X     = (const float*)d_in[0];
  const float* beta0 = (const float*)d_in[1];
  const float* beta  = (const float*)d_in[2];
  const float* Theta = (const float*)d_in[3];
  float* y = (float*)d_out;

  init_y<<<N_ROWS / 256, 256, 0, stream>>>(y, beta0);
  fused_quad_kernel<<<(N_ROWS / BM) * (P_DIM / BN), 256, 0, stream>>>(X, beta, Theta, y);
}

// Round 2
// 255.775 us; speedup vs baseline: 1.6322x; 1.6322x over previous
//
#include <hip/hip_runtime.h>

// y[n] = beta0 + sum_c X[n,c]*(beta[c] + Z[n,c]),  Z = X @ triu(Theta,1)
// R2: pre-convert X->bf16 and Theta->triu-masked-transposed bf16 into d_ws,
// then m97-structure MFMA GEMM (global_load_lds width=16, linear LDS, 2-barrier)
// with triangular K-skip + fused row-dot epilogue. XCD-swizzled grid.

typedef __bf16 bf16_t;
typedef bf16_t bf16x8 __attribute__((ext_vector_type(8)));
typedef float f32x4 __attribute__((ext_vector_type(4)));
typedef unsigned short u16;
typedef u16 u16x4 __attribute__((ext_vector_type(4)));
typedef u16 u16x8 __attribute__((ext_vector_type(8)));

#define N_ROWS 65536
#define P_DIM  1024
#define BM 128
#define BN 128
#define BK 32

static __device__ __forceinline__ u16 f2bf(float f) {
  unsigned u = __builtin_bit_cast(unsigned, f);
  u += 0x7FFFu + ((u >> 16) & 1u);   // round-to-nearest-even
  return (u16)(u >> 16);
}
static __device__ __forceinline__ float bf2f(u16 v) {
  return __builtin_bit_cast(float, ((unsigned)v) << 16);
}

// global(16B/lane) -> LDS direct. LDS dest must be WAVE-UNIFORM base; HW adds lane*16.
static __device__ __forceinline__ void gload16(const void* g, void* lds_base) {
  __builtin_amdgcn_global_load_lds(
      (const __attribute__((address_space(1))) unsigned char*)g,
      (__attribute__((address_space(3))) unsigned char*)lds_base, 16, 0, 0);
}

__global__ void __launch_bounds__(256)
init_y(float* __restrict__ y, const float* __restrict__ beta0) {
  int i = blockIdx.x * blockDim.x + threadIdx.x;
  if (i < N_ROWS) y[i] = beta0[0];
}

// ---- conversion pass 1: X f32 -> bf16 (grid-stride, 8 elems/thread/iter) ----
__global__ void __launch_bounds__(256)
conv_x(const float* __restrict__ X, u16* __restrict__ Xb) {
  const size_t total8 = (size_t)N_ROWS * P_DIM / 8;
  const size_t stride = (size_t)gridDim.x * 256;
  for (size_t i = (size_t)blockIdx.x * 256 + threadIdx.x; i < total8; i += stride) {
    f32x4 a = *(const f32x4*)(X + i * 8);
    f32x4 b = *(const f32x4*)(X + i * 8 + 4);
    u16x8 w;
    #pragma unroll
    for (int j = 0; j < 4; ++j) { w[j] = f2bf(a[j]); w[j + 4] = f2bf(b[j]); }
    *(u16x8*)(Xb + i * 8) = w;
  }
}

// ---- conversion pass 2: Tt[c][k] = (k<c) ? bf16(Theta[k][c]) : 0 ----
__global__ void __launch_bounds__(256)
conv_theta(const float* __restrict__ Theta, u16* __restrict__ Tt) {
  __shared__ float tile[32][33];
  const int tx = threadIdx.x;          // 0..31
  const int ty = threadIdx.y;          // 0..7
  const int k0 = blockIdx.x * 32;
  const int c0 = blockIdx.y * 32;
  #pragma unroll
  for (int i = 0; i < 4; ++i) {
    int kl = ty + 8 * i;
    tile[kl][tx] = Theta[(size_t)(k0 + kl) * P_DIM + c0 + tx];
  }
  __syncthreads();
  #pragma unroll
  for (int i = 0; i < 4; ++i) {
    int cl = ty + 8 * i;
    int c = c0 + cl, k = k0 + tx;
    float v = tile[tx][cl];
    Tt[(size_t)c * P_DIM + k] = (k < c) ? f2bf(v) : (u16)0;
  }
}

// ---- main GEMM + fused epilogue (bf16 inputs from ws) ----
__global__ void __launch_bounds__(256)
gemm_bf16_kernel(const u16* __restrict__ Xb, const u16* __restrict__ Tt,
                 const float* __restrict__ beta, float* __restrict__ y)
{
  __shared__ __align__(16) u16 Alds[BM * BK];   // [128][32] linear, 8 KB
  __shared__ __align__(16) u16 Blds[BN * BK];   // [128][32] linear (rows = Theta cols)

  // XCD bijective swizzle (4096 % 8 == 0): 8 sibling column-blocks of one
  // row-panel land on the SAME XCD -> A-panel L2 reuse.
  const int nwg = (N_ROWS / BM) * (P_DIM / BN);   // 4096
  const int swz = (blockIdx.x & 7) * (nwg / 8) + (blockIdx.x >> 3);
  const int bn  = swz & 7;
  const int bm  = swz >> 3;
  const int c0  = bn * BN;
  const int m0  = bm * BM;
  const int nkt = (bn + 1) * (BN / BK);           // triangular K-skip

  const int tid  = threadIdx.x;
  const int lane = tid & 63;
  const int wid  = tid >> 6;
  const int wm   = wid >> 1;
  const int wn   = wid & 1;
  const int l15  = lane & 15;
  const int lg   = lane >> 4;

  // staging geometry: chunk = 1 KB of LDS (one wave-load); 8 chunks per 8 KB tile;
  // each of 4 waves issues 2 chunks per tile. lane covers row c*16+(lane>>2), col (lane&3)*8.
  const int srow = lane >> 2;
  const int sce  = (lane & 3) * 8;

  f32x4 acc[4][4];
  #pragma unroll
  for (int i = 0; i < 4; ++i)
    #pragma unroll
    for (int j = 0; j < 4; ++j)
      acc[i][j] = (f32x4)0.0f;

  for (int kt = 0; kt < nkt; ++kt) {
    const int k0 = kt * BK;
    // ---- stage A & B direct to LDS ----
    #pragma unroll
    for (int q = 0; q < 2; ++q) {
      const int c = wid * 2 + q;           // chunk 0..7
      const int row = c * 16 + srow;
      gload16(Xb + (size_t)(m0 + row) * P_DIM + k0 + sce, &Alds[c * 512]);
      gload16(Tt + (size_t)(c0 + row) * P_DIM + k0 + sce, &Blds[c * 512]);
    }
    __syncthreads();   // drains vmcnt: staged tiles visible

    // ---- fragments + MFMA ----
    bf16x8 af[4], bfr[4];
    #pragma unroll
    for (int mi = 0; mi < 4; ++mi) {
      u16x8 t = *(const u16x8*)&Alds[(wm * 64 + mi * 16 + l15) * BK + lg * 8];
      af[mi] = __builtin_bit_cast(bf16x8, t);
    }
    #pragma unroll
    for (int ni = 0; ni < 4; ++ni) {
      u16x8 t = *(const u16x8*)&Blds[(wn * 64 + ni * 16 + l15) * BK + lg * 8];
      bfr[ni] = __builtin_bit_cast(bf16x8, t);
    }
    #pragma unroll
    for (int mi = 0; mi < 4; ++mi)
      #pragma unroll
      for (int ni = 0; ni < 4; ++ni)
        acc[mi][ni] = __builtin_amdgcn_mfma_f32_16x16x32_bf16(af[mi], bfr[ni], acc[mi][ni], 0, 0, 0);

    __syncthreads();   // protect LDS before next stage overwrites
  }

  // ---- epilogue: y_partial[row] = sum_c (Z[row,c] + beta[c]) * X[row,c] ----
  // C/D layout: col = lane&15, row = (lane>>4)*4 + reg
  float ysum[4][4];
  #pragma unroll
  for (int mi = 0; mi < 4; ++mi)
    #pragma unroll
    for (int r = 0; r < 4; ++r)
      ysum[mi][r] = 0.0f;

  #pragma unroll
  for (int ni = 0; ni < 4; ++ni) {
    const int col = c0 + wn * 64 + ni * 16 + l15;
    const float bta = beta[col];
    #pragma unroll
    for (int mi = 0; mi < 4; ++mi) {
      const int rowb = m0 + wm * 64 + mi * 16 + lg * 4;
      #pragma unroll
      for (int r = 0; r < 4; ++r) {
        float xv = bf2f(Xb[(size_t)(rowb + r) * P_DIM + col]);   // L3/L2-hot
        ysum[mi][r] += (acc[mi][ni][r] + bta) * xv;
      }
    }
  }

  #pragma unroll
  for (int m = 1; m < 16; m <<= 1)
    #pragma unroll
    for (int mi = 0; mi < 4; ++mi)
      #pragma unroll
      for (int r = 0; r < 4; ++r)
        ysum[mi][r] += __shfl_xor(ysum[mi][r], m);

  if (l15 == 0) {
    #pragma unroll
    for (int mi = 0; mi < 4; ++mi)
      #pragma unroll
      for (int r = 0; r < 4; ++r)
        atomicAdd(&y[m0 + wm * 64 + mi * 16 + lg * 4 + r], ysum[mi][r]);
  }
}

// ================= fallback (R1 kernel) if ws too small =================
#define LDT 40
__global__ void __launch_bounds__(256)
fused_quad_fallback(const float* __restrict__ X, const float* __restrict__ beta,
                    const float* __restrict__ Theta, float* __restrict__ y)
{
  __shared__ __align__(16) u16 Alds[BM * LDT];
  __shared__ __align__(16) u16 Blds[BN * LDT];

  const int bid = blockIdx.x;
  const int bn  = bid & 7;
  const int bm  = bid >> 3;
  const int c0  = bn * BN;
  const int m0  = bm * BM;
  const int nkt = (bn + 1) * (BN / BK);

  const int tid  = threadIdx.x;
  const int lane = tid & 63;
  const int wid  = tid >> 6;
  const int wm   = wid >> 1;
  const int wn   = wid & 1;
  const int l15  = lane & 15;
  const int lg   = lane >> 4;

  f32x4 acc[4][4];
  #pragma unroll
  for (int i = 0; i < 4; ++i)
    #pragma unroll
    for (int j = 0; j < 4; ++j)
      acc[i][j] = (f32x4)0.0f;

  const int arow  = tid >> 1;
  const int ahalf = (tid & 1) * 16;
  const int kb4 = (tid >> 5) * 4;
  const int cb4 = (tid & 31) * 4;

  for (int kt = 0; kt < nkt; ++kt) {
    const int k0 = kt * BK;
    __syncthreads();
    {
      const f32x4* p = (const f32x4*)(X + (size_t)(m0 + arow) * P_DIM + k0 + ahalf);
      f32x4 v0 = p[0], v1 = p[1], v2 = p[2], v3 = p[3];
      u16x8 w0, w1;
      #pragma unroll
      for (int i = 0; i < 4; ++i) {
        w0[i] = f2bf(v0[i]); w0[i + 4] = f2bf(v1[i]);
        w1[i] = f2bf(v2[i]); w1[i + 4] = f2bf(v3[i]);
      }
      *(u16x8*)&Alds[arow * LDT + ahalf]     = w0;
      *(u16x8*)&Alds[arow * LDT + ahalf + 8] = w1;
    }
    {
      float e[4][4];
      #pragma unroll
      for (int i = 0; i < 4; ++i) {
        f32x4 r = *(const f32x4*)(Theta + (size_t)(k0 + kb4 + i) * P_DIM + c0 + cb4);
        #pragma unroll
        for (int j = 0; j < 4; ++j)
          e[i][j] = ((k0 + kb4 + i) < (c0 + cb4 + j)) ? r[j] : 0.0f;
      }
      #pragma unroll
      for (int j = 0; j < 4; ++j) {
        u16x4 wv;
        #pragma unroll
        for (int i = 0; i < 4; ++i) wv[i] = f2bf(e[i][j]);
        *(u16x4*)&Blds[(cb4 + j) * LDT + kb4] = wv;
      }
    }
    __syncthreads();

    bf16x8 af[4], bfr[4];
    #pragma unroll
    for (int mi = 0; mi < 4; ++mi) {
      u16x8 t = *(const u16x8*)&Alds[(wm * 64 + mi * 16 + l15) * LDT + lg * 8];
      af[mi] = __builtin_bit_cast(bf16x8, t);
    }
    #pragma unroll
    for (int ni = 0; ni < 4; ++ni) {
      u16x8 t = *(const u16x8*)&Blds[(wn * 64 + ni * 16 + l15) * LDT + lg * 8];
      bfr[ni] = __builtin_bit_cast(bf16x8, t);
    }
    #pragma unroll
    for (int mi = 0; mi < 4; ++mi)
      #pragma unroll
      for (int ni = 0; ni < 4; ++ni)
        acc[mi][ni] = __builtin_amdgcn_mfma_f32_16x16x32_bf16(af[mi], bfr[ni], acc[mi][ni], 0, 0, 0);
  }

  float ysum[4][4];
  #pragma unroll
  for (int mi = 0; mi < 4; ++mi)
    #pragma unroll
    for (int r = 0; r < 4; ++r)
      ysum[mi][r] = 0.0f;

  #pragma unroll
  for (int ni = 0; ni < 4; ++ni) {
    const int col = c0 + wn * 64 + ni * 16 + l15;
    const float bta = beta[col];
    #pragma unroll
    for (int mi = 0; mi < 4; ++mi) {
      const int rowb = m0 + wm * 64 + mi * 16 + lg * 4;
      #pragma unroll
      for (int r = 0; r < 4; ++r) {
        float xv = X[(size_t)(rowb + r) * P_DIM + col];
        ysum[mi][r] += (acc[mi][ni][r] + bta) * xv;
      }
    }
  }

  #pragma unroll
  for (int m = 1; m < 16; m <<= 1)
    #pragma unroll
    for (int mi = 0; mi < 4; ++mi)
      #pragma unroll
      for (int r = 0; r < 4; ++r)
        ysum[mi][r] += __shfl_xor(ysum[mi][r], m);

  if (l15 == 0) {
    #pragma unroll
    for (int mi = 0; mi < 4; ++mi)
      #pragma unroll
      for (int r = 0; r < 4; ++r)
        atomicAdd(&y[m0 + wm * 64 + mi * 16 + lg * 4 + r], ysum[mi][r]);
  }
}

extern "C" void kernel_launch(void* const* d_in, const int* in_sizes, int n_in,
                              void* d_out, int out_size, void* d_ws, size_t ws_size,
                              hipStream_t stream) {
  const float* X     = (const float*)d_in[0];
  const float* beta0 = (const float*)d_in[1];
  const float* beta  = (const float*)d_in[2];
  const float* Theta = (const float*)d_in[3];
  float* y = (float*)d_out;

  init_y<<<N_ROWS / 256, 256, 0, stream>>>(y, beta0);

  const size_t need = (size_t)N_ROWS * P_DIM * 2 + (size_t)P_DIM * P_DIM * 2;
  if (ws_size >= need) {
    u16* Xb = (u16*)d_ws;
    u16* Tt = Xb + (size_t)N_ROWS * P_DIM;
    conv_x<<<2048, 256, 0, stream>>>(X, Xb);
    conv_theta<<<dim3(32, 32), dim3(32, 8), 0, stream>>>(Theta, Tt);
    gemm_bf16_kernel<<<(N_ROWS / BM) * (P_DIM / BN), 256, 0, stream>>>(Xb, Tt, beta, y);
  } else {
    fused_quad_fallback<<<(N_ROWS / BM) * (P_DIM / BN), 256, 0, stream>>>(X, beta, Theta, y);
  }
}

// Round 3
// 210.024 us; speedup vs baseline: 1.9878x; 1.2178x over previous
//
#include <hip/hip_runtime.h>

// y[n] = beta0 + sum_c X[n,c]*(beta[c] + Z[n,c]),  Z = X @ triu(Theta,1)
// R3: pre-convert X->bf16, Theta->triu^T bf16 (d_ws); GEMM now uses
// DOUBLE-BUFFERED 2-phase K-loop (stage t+1 issued before MFMA of t, one
// barrier per step) + heavy-blocks-first dispatch. XCD-swizzled grid.

typedef __bf16 bf16_t;
typedef bf16_t bf16x8 __attribute__((ext_vector_type(8)));
typedef float f32x4 __attribute__((ext_vector_type(4)));
typedef unsigned short u16;
typedef u16 u16x4 __attribute__((ext_vector_type(4)));
typedef u16 u16x8 __attribute__((ext_vector_type(8)));

#define N_ROWS 65536
#define P_DIM  1024
#define BM 128
#define BN 128
#define BK 32

static __device__ __forceinline__ u16 f2bf(float f) {
  unsigned u = __builtin_bit_cast(unsigned, f);
  u += 0x7FFFu + ((u >> 16) & 1u);   // round-to-nearest-even
  return (u16)(u >> 16);
}
static __device__ __forceinline__ float bf2f(u16 v) {
  return __builtin_bit_cast(float, ((unsigned)v) << 16);
}

// global(16B/lane) -> LDS direct. LDS dest must be WAVE-UNIFORM base; HW adds lane*16.
static __device__ __forceinline__ void gload16(const void* g, void* lds_base) {
  __builtin_amdgcn_global_load_lds(
      (const __attribute__((address_space(1))) unsigned char*)g,
      (__attribute__((address_space(3))) unsigned char*)lds_base, 16, 0, 0);
}

__global__ void __launch_bounds__(256)
init_y(float* __restrict__ y, const float* __restrict__ beta0) {
  int i = blockIdx.x * blockDim.x + threadIdx.x;
  if (i < N_ROWS) y[i] = beta0[0];
}

// ---- conversion pass 1: X f32 -> bf16 ----
__global__ void __launch_bounds__(256)
conv_x(const float* __restrict__ X, u16* __restrict__ Xb) {
  const size_t total8 = (size_t)N_ROWS * P_DIM / 8;
  const size_t stride = (size_t)gridDim.x * 256;
  for (size_t i = (size_t)blockIdx.x * 256 + threadIdx.x; i < total8; i += stride) {
    f32x4 a = *(const f32x4*)(X + i * 8);
    f32x4 b = *(const f32x4*)(X + i * 8 + 4);
    u16x8 w;
    #pragma unroll
    for (int j = 0; j < 4; ++j) { w[j] = f2bf(a[j]); w[j + 4] = f2bf(b[j]); }
    *(u16x8*)(Xb + i * 8) = w;
  }
}

// ---- conversion pass 2: Tt[c][k] = (k<c) ? bf16(Theta[k][c]) : 0 ----
__global__ void __launch_bounds__(256)
conv_theta(const float* __restrict__ Theta, u16* __restrict__ Tt) {
  __shared__ float tile[32][33];
  const int tx = threadIdx.x;          // 0..31
  const int ty = threadIdx.y;          // 0..7
  const int k0 = blockIdx.x * 32;
  const int c0 = blockIdx.y * 32;
  #pragma unroll
  for (int i = 0; i < 4; ++i) {
    int kl = ty + 8 * i;
    tile[kl][tx] = Theta[(size_t)(k0 + kl) * P_DIM + c0 + tx];
  }
  __syncthreads();
  #pragma unroll
  for (int i = 0; i < 4; ++i) {
    int cl = ty + 8 * i;
    int c = c0 + cl, k = k0 + tx;
    float v = tile[tx][cl];
    Tt[(size_t)c * P_DIM + k] = (k < c) ? f2bf(v) : (u16)0;
  }
}

// ---- main GEMM + fused epilogue, double-buffered 2-phase ----
__global__ void __launch_bounds__(256)
gemm_bf16_db(const u16* __restrict__ Xb, const u16* __restrict__ Tt,
             const float* __restrict__ beta, float* __restrict__ y)
{
  __shared__ __align__(16) u16 Alds[2][BM * BK];   // 2 x 8 KB
  __shared__ __align__(16) u16 Blds[2][BN * BK];   // 2 x 8 KB

  // XCD bijective swizzle: same-XCD consecutive blocks share bm (A-panel L2 reuse).
  const int nwg = (N_ROWS / BM) * (P_DIM / BN);    // 4096
  const int swz = (blockIdx.x & 7) * (nwg / 8) + (blockIdx.x >> 3);
  const int bn  = 7 - (swz & 7);                   // heavy (long-K) blocks first
  const int bm  = swz >> 3;
  const int c0  = bn * BN;
  const int m0  = bm * BM;
  const int nkt = (bn + 1) * (BN / BK);            // triangular K-skip (>=4)

  const int tid  = threadIdx.x;
  const int lane = tid & 63;
  const int wid  = tid >> 6;
  const int wm   = wid >> 1;
  const int wn   = wid & 1;
  const int l15  = lane & 15;
  const int lg   = lane >> 4;

  // staging geometry: chunk = 1 KB (one wave-load, 64 lanes x 16B);
  // chunk c covers rows [c*16, c*16+16), lane covers row c*16+(lane>>2), k (lane&3)*8.
  const int srow = lane >> 2;
  const int sce  = (lane & 3) * 8;

  f32x4 acc[4][4];
  #pragma unroll
  for (int i = 0; i < 4; ++i)
    #pragma unroll
    for (int j = 0; j < 4; ++j)
      acc[i][j] = (f32x4)0.0f;

  #define STAGE(buf, kt_)                                                        \
    {                                                                            \
      const int k0_ = (kt_) * BK;                                                \
      _Pragma("unroll")                                                          \
      for (int q = 0; q < 2; ++q) {                                              \
        const int c_ = wid * 2 + q;                                              \
        const int row_ = c_ * 16 + srow;                                         \
        gload16(Xb + (size_t)(m0 + row_) * P_DIM + k0_ + sce, &Alds[buf][c_ * 512]); \
        gload16(Tt + (size_t)(c0 + row_) * P_DIM + k0_ + sce, &Blds[buf][c_ * 512]); \
      }                                                                          \
    }

  // prologue: stage tile 0 into buf 0
  STAGE(0, 0)

  for (int kt = 0; kt < nkt - 1; ++kt) {
    const int cur = kt & 1;
    __syncthreads();   // drains my vmcnt -> stage(kt) visible; buf[cur^1] readers done

    bf16x8 af[4], bfr[4];
    #pragma unroll
    for (int mi = 0; mi < 4; ++mi) {
      u16x8 t = *(const u16x8*)&Alds[cur][(wm * 64 + mi * 16 + l15) * BK + lg * 8];
      af[mi] = __builtin_bit_cast(bf16x8, t);
    }
    #pragma unroll
    for (int ni = 0; ni < 4; ++ni) {
      u16x8 t = *(const u16x8*)&Blds[cur][(wn * 64 + ni * 16 + l15) * BK + lg * 8];
      bfr[ni] = __builtin_bit_cast(bf16x8, t);
    }

    // issue next-tile loads BEFORE the MFMA cluster: latency hides under compute
    STAGE(cur ^ 1, kt + 1)

    #pragma unroll
    for (int mi = 0; mi < 4; ++mi)
      #pragma unroll
      for (int ni = 0; ni < 4; ++ni)
        acc[mi][ni] = __builtin_amdgcn_mfma_f32_16x16x32_bf16(af[mi], bfr[ni], acc[mi][ni], 0, 0, 0);
  }

  // epilogue iteration (no prefetch)
  {
    const int cur = (nkt - 1) & 1;
    __syncthreads();
    bf16x8 af[4], bfr[4];
    #pragma unroll
    for (int mi = 0; mi < 4; ++mi) {
      u16x8 t = *(const u16x8*)&Alds[cur][(wm * 64 + mi * 16 + l15) * BK + lg * 8];
      af[mi] = __builtin_bit_cast(bf16x8, t);
    }
    #pragma unroll
    for (int ni = 0; ni < 4; ++ni) {
      u16x8 t = *(const u16x8*)&Blds[cur][(wn * 64 + ni * 16 + l15) * BK + lg * 8];
      bfr[ni] = __builtin_bit_cast(bf16x8, t);
    }
    #pragma unroll
    for (int mi = 0; mi < 4; ++mi)
      #pragma unroll
      for (int ni = 0; ni < 4; ++ni)
        acc[mi][ni] = __builtin_amdgcn_mfma_f32_16x16x32_bf16(af[mi], bfr[ni], acc[mi][ni], 0, 0, 0);
  }
  #undef STAGE

  // ---- epilogue: y_partial[row] = sum_c (Z[row,c] + beta[c]) * X[row,c] ----
  // C/D layout: col = lane&15, row = (lane>>4)*4 + reg
  float ysum[4][4];
  #pragma unroll
  for (int mi = 0; mi < 4; ++mi)
    #pragma unroll
    for (int r = 0; r < 4; ++r)
      ysum[mi][r] = 0.0f;

  #pragma unroll
  for (int ni = 0; ni < 4; ++ni) {
    const int col = c0 + wn * 64 + ni * 16 + l15;
    const float bta = beta[col];
    #pragma unroll
    for (int mi = 0; mi < 4; ++mi) {
      const int rowb = m0 + wm * 64 + mi * 16 + lg * 4;
      #pragma unroll
      for (int r = 0; r < 4; ++r) {
        float xv = bf2f(Xb[(size_t)(rowb + r) * P_DIM + col]);   // L3/L2-hot
        ysum[mi][r] += (acc[mi][ni][r] + bta) * xv;
      }
    }
  }

  #pragma unroll
  for (int m = 1; m < 16; m <<= 1)
    #pragma unroll
    for (int mi = 0; mi < 4; ++mi)
      #pragma unroll
      for (int r = 0; r < 4; ++r)
        ysum[mi][r] += __shfl_xor(ysum[mi][r], m);

  if (l15 == 0) {
    #pragma unroll
    for (int mi = 0; mi < 4; ++mi)
      #pragma unroll
      for (int r = 0; r < 4; ++r)
        atomicAdd(&y[m0 + wm * 64 + mi * 16 + lg * 4 + r], ysum[mi][r]);
  }
}

// ================= fallback (R1 kernel) if ws too small =================
#define LDT 40
__global__ void __launch_bounds__(256)
fused_quad_fallback(const float* __restrict__ X, const float* __restrict__ beta,
                    const float* __restrict__ Theta, float* __restrict__ y)
{
  __shared__ __align__(16) u16 Alds[BM * LDT];
  __shared__ __align__(16) u16 Blds[BN * LDT];

  const int bid = blockIdx.x;
  const int bn  = bid & 7;
  const int bm  = bid >> 3;
  const int c0  = bn * BN;
  const int m0  = bm * BM;
  const int nkt = (bn + 1) * (BN / BK);

  const int tid  = threadIdx.x;
  const int lane = tid & 63;
  const int wid  = tid >> 6;
  const int wm   = wid >> 1;
  const int wn   = wid & 1;
  const int l15  = lane & 15;
  const int lg   = lane >> 4;

  f32x4 acc[4][4];
  #pragma unroll
  for (int i = 0; i < 4; ++i)
    #pragma unroll
    for (int j = 0; j < 4; ++j)
      acc[i][j] = (f32x4)0.0f;

  const int arow  = tid >> 1;
  const int ahalf = (tid & 1) * 16;
  const int kb4 = (tid >> 5) * 4;
  const int cb4 = (tid & 31) * 4;

  for (int kt = 0; kt < nkt; ++kt) {
    const int k0 = kt * BK;
    __syncthreads();
    {
      const f32x4* p = (const f32x4*)(X + (size_t)(m0 + arow) * P_DIM + k0 + ahalf);
      f32x4 v0 = p[0], v1 = p[1], v2 = p[2], v3 = p[3];
      u16x8 w0, w1;
      #pragma unroll
      for (int i = 0; i < 4; ++i) {
        w0[i] = f2bf(v0[i]); w0[i + 4] = f2bf(v1[i]);
        w1[i] = f2bf(v2[i]); w1[i + 4] = f2bf(v3[i]);
      }
      *(u16x8*)&Alds[arow * LDT + ahalf]     = w0;
      *(u16x8*)&Alds[arow * LDT + ahalf + 8] = w1;
    }
    {
      float e[4][4];
      #pragma unroll
      for (int i = 0; i < 4; ++i) {
        f32x4 r = *(const f32x4*)(Theta + (size_t)(k0 + kb4 + i) * P_DIM + c0 + cb4);
        #pragma unroll
        for (int j = 0; j < 4; ++j)
          e[i][j] = ((k0 + kb4 + i) < (c0 + cb4 + j)) ? r[j] : 0.0f;
      }
      #pragma unroll
      for (int j = 0; j < 4; ++j) {
        u16x4 wv;
        #pragma unroll
        for (int i = 0; i < 4; ++i) wv[i] = f2bf(e[i][j]);
        *(u16x4*)&Blds[(cb4 + j) * LDT + kb4] = wv;
      }
    }
    __syncthreads();

    bf16x8 af[4], bfr[4];
    #pragma unroll
    for (int mi = 0; mi < 4; ++mi) {
      u16x8 t = *(const u16x8*)&Alds[(wm * 64 + mi * 16 + l15) * LDT + lg * 8];
      af[mi] = __builtin_bit_cast(bf16x8, t);
    }
    #pragma unroll
    for (int ni = 0; ni < 4; ++ni) {
      u16x8 t = *(const u16x8*)&Blds[(wn * 64 + ni * 16 + l15) * LDT + lg * 8];
      bfr[ni] = __builtin_bit_cast(bf16x8, t);
    }
    #pragma unroll
    for (int mi = 0; mi < 4; ++mi)
      #pragma unroll
      for (int ni = 0; ni < 4; ++ni)
        acc[mi][ni] = __builtin_amdgcn_mfma_f32_16x16x32_bf16(af[mi], bfr[ni], acc[mi][ni], 0, 0, 0);
  }

  float ysum[4][4];
  #pragma unroll
  for (int mi = 0; mi < 4; ++mi)
    #pragma unroll
    for (int r = 0; r < 4; ++r)
      ysum[mi][r] = 0.0f;

  #pragma unroll
  for (int ni = 0; ni < 4; ++ni) {
    const int col = c0 + wn * 64 + ni * 16 + l15;
    const float bta = beta[col];
    #pragma unroll
    for (int mi = 0; mi < 4; ++mi) {
      const int rowb = m0 + wm * 64 + mi * 16 + lg * 4;
      #pragma unroll
      for (int r = 0; r < 4; ++r) {
        float xv = X[(size_t)(rowb + r) * P_DIM + col];
        ysum[mi][r] += (acc[mi][ni][r] + bta) * xv;
      }
    }
  }

  #pragma unroll
  for (int m = 1; m < 16; m <<= 1)
    #pragma unroll
    for (int mi = 0; mi < 4; ++mi)
      #pragma unroll
      for (int r = 0; r < 4; ++r)
        ysum[mi][r] += __shfl_xor(ysum[mi][r], m);

  if (l15 == 0) {
    #pragma unroll
    for (int mi = 0; mi < 4; ++mi)
      #pragma unroll
      for (int r = 0; r < 4; ++r)
        atomicAdd(&y[m0 + wm * 64 + mi * 16 + lg * 4 + r], ysum[mi][r]);
  }
}

extern "C" void kernel_launch(void* const* d_in, const int* in_sizes, int n_in,
                              void* d_out, int out_size, void* d_ws, size_t ws_size,
                              hipStream_t stream) {
  const float* X     = (const float*)d_in[0];
  const float* beta0 = (const float*)d_in[1];
  const float* beta  = (const float*)d_in[2];
  const float* Theta = (const float*)d_in[3];
  float* y = (float*)d_out;

  init_y<<<N_ROWS / 256, 256, 0, stream>>>(y, beta0);

  const size_t need = (size_t)N_ROWS * P_DIM * 2 + (size_t)P_DIM * P_DIM * 2;
  if (ws_size >= need) {
    u16* Xb = (u16*)d_ws;
    u16* Tt = Xb + (size_t)N_ROWS * P_DIM;
    conv_x<<<2048, 256, 0, stream>>>(X, Xb);
    conv_theta<<<dim3(32, 32), dim3(32, 8), 0, stream>>>(Theta, Tt);
    gemm_bf16_db<<<(N_ROWS / BM) * (P_DIM / BN), 256, 0, stream>>>(Xb, Tt, beta, y);
  } else {
    fused_quad_fallback<<<(N_ROWS / BM) * (P_DIM / BN), 256, 0, stream>>>(X, beta, Theta, y);
  }
}